// Round 2
// baseline (328.202 us; speedup 1.0000x reference)
//
#include <hip/hip_runtime.h>
#include <math.h>

typedef __attribute__((ext_vector_type(8))) short short8;
typedef __attribute__((ext_vector_type(4))) float f32x4;
typedef unsigned short bf16_t;

#define GLOAD_LDS16(g, l)                                                   \
    __builtin_amdgcn_global_load_lds(                                       \
        (__attribute__((address_space(1))) void*)(g),                       \
        (__attribute__((address_space(3))) void*)(l), 16, 0, 0)

__device__ __forceinline__ bf16_t f2b_rne(float f) {
    unsigned int u = __float_as_uint(f);
    u += 0x7FFFu + ((u >> 16) & 1u);
    return (bf16_t)(u >> 16);
}

__device__ __forceinline__ void store_out(bf16_t* p, float v) { *p = f2b_rne(v); }
__device__ __forceinline__ void store_out(float* p, float v) { *p = v; }

// ---------------------------------------------------------------------------
// fp32 -> bf16 conversion, 4 elems/thread, grid-stride
// ---------------------------------------------------------------------------
__global__ __launch_bounds__(256) void f2b_kernel(const float* __restrict__ in,
                                                  bf16_t* __restrict__ out, int n4) {
    int stride = gridDim.x * 256;
    for (int i = blockIdx.x * 256 + threadIdx.x; i < n4; i += stride) {
        float4 v = ((const float4*)in)[i];
        ushort4 p;
        p.x = f2b_rne(v.x); p.y = f2b_rne(v.y);
        p.z = f2b_rne(v.z); p.w = f2b_rne(v.w);
        ((ushort4*)out)[i] = p;
    }
}

// ---------------------------------------------------------------------------
// Relative-position bias table: tab[h][(k-q)+1023], h=0..15, diag in [-1023,1023]
// Exact f32 replication of the reference bucket math (knife-edges 16/32/64 are
// exact in f32: log(2^k) reduces exactly, divisor = 4*f32(ln2)).
// ---------------------------------------------------------------------------
__global__ void build_bias_tab(const float* __restrict__ emb, float* __restrict__ tab) {
    int idx = blockIdx.x * 256 + threadIdx.x;
    if (idx >= 2047) return;
    int rel = idx - 1023;                 // k - q
    int rb = rel > 0 ? 16 : 0;
    int rp = rel < 0 ? -rel : rel;
    int bucket;
    if (rp < 8) {
        bucket = rb + rp;
    } else {
        float t = logf((float)rp * 0.125f);
        int vi = 8 + (int)(t / 2.772588722239781f * 8.0f);
        bucket = rb + (vi < 15 ? vi : 15);
    }
    #pragma unroll
    for (int hh = 0; hh < 16; hh++)
        tab[hh * 2048 + idx] = emb[bucket * 16 + hh];
}

// ---------------------------------------------------------------------------
// bf16 MFMA GEMM (m97 structure): C[M,N] = A[M,1024] * B[N,1024]^T
// 128x128 tile, BK=32, 256 thr / 4 waves (2x2), 4x4 16x16 frags per wave.
// global_load_lds width-16 staging into linear LDS; 16 MFMA / K-step / wave.
// ---------------------------------------------------------------------------
template <typename OT>
__global__ __launch_bounds__(256) void gemm_mfma(const bf16_t* __restrict__ A,
                                                 const bf16_t* __restrict__ B,
                                                 OT* __restrict__ C, int N) {
    __shared__ __align__(16) bf16_t As[128 * 32];
    __shared__ __align__(16) bf16_t Bs[128 * 32];
    const int tid = threadIdx.x;
    const int lane = tid & 63;
    const int wv = tid >> 6;
    const int wr = wv >> 1, wc = wv & 1;
    const int m0 = blockIdx.y * 128, n0 = blockIdx.x * 128;
    const int cc = lane & 15, cg = lane >> 4;

    f32x4 acc[4][4];
    #pragma unroll
    for (int i = 0; i < 4; i++)
        #pragma unroll
        for (int j = 0; j < 4; j++) acc[i][j] = {0.f, 0.f, 0.f, 0.f};

    for (int k0 = 0; k0 < 1024; k0 += 32) {
        __syncthreads();  // prior-iter LDS reads done before overwrite
        #pragma unroll
        for (int it = 0; it < 2; it++) {
            int c = it * 256 + tid;
            int r = c >> 2, kc = (c & 3) * 8;
            GLOAD_LDS16(A + (size_t)(m0 + r) * 1024 + k0 + kc, &As[c * 8]);
            GLOAD_LDS16(B + (size_t)(n0 + r) * 1024 + k0 + kc, &Bs[c * 8]);
        }
        __syncthreads();  // compiler drains vmcnt before s_barrier

        short8 af[4], bf[4];
        #pragma unroll
        for (int mf = 0; mf < 4; mf++)
            af[mf] = *(const short8*)&As[(wr * 64 + mf * 16 + cc) * 32 + cg * 8];
        #pragma unroll
        for (int nf = 0; nf < 4; nf++)
            bf[nf] = *(const short8*)&Bs[(wc * 64 + nf * 16 + cc) * 32 + cg * 8];
        #pragma unroll
        for (int mf = 0; mf < 4; mf++)
            #pragma unroll
            for (int nf = 0; nf < 4; nf++)
                acc[mf][nf] = __builtin_amdgcn_mfma_f32_16x16x32_bf16(
                    af[mf], bf[nf], acc[mf][nf], 0, 0, 0);
    }

    // epilogue: D layout col=lane&15, row=(lane>>4)*4+j (m89-verified)
    #pragma unroll
    for (int mf = 0; mf < 4; mf++)
        #pragma unroll
        for (int j = 0; j < 4; j++) {
            size_t row = (size_t)(m0 + wr * 64 + mf * 16 + cg * 4 + j);
            OT* cp = C + row * N + n0 + wc * 64 + cc;
            #pragma unroll
            for (int nf = 0; nf < 4; nf++) store_out(cp + nf * 16, acc[mf][nf][j]);
        }
}

// ---------------------------------------------------------------------------
// MFMA flash attention. Grid (16 qtiles, 16 heads, 8 batch), 256 thr / 4 waves.
// Block: 64 q-rows; wave w owns q rows w*16..w*16+15. K-tiles of 64.
// LDS tiles row-major [64][64] bf16, 16B-slot XOR swizzle g(r)=(r+(r>>3))&7.
// ---------------------------------------------------------------------------
#define GSWZ(r) (((r) + ((r) >> 3)) & 7)

__global__ __launch_bounds__(256) void attn_mfma(const bf16_t* __restrict__ qkv,
                                                 const float* __restrict__ tab,
                                                 bf16_t* __restrict__ attn_out) {
    __shared__ __align__(16) bf16_t Qs[64 * 64];
    __shared__ __align__(16) bf16_t Ks[64 * 64];
    __shared__ __align__(16) bf16_t Vt[64 * 64];   // [d][key]
    __shared__ __align__(16) bf16_t Pl[64 * 64];   // [q][key]
    __shared__ float bias_s[1088];

    const int tid = threadIdx.x;
    const int lane = tid & 63;
    const int w = tid >> 6;
    const int cc = lane & 15, cg = lane >> 4;
    const int q0 = blockIdx.x * 64;
    const int h = blockIdx.y;
    const int b = blockIdx.z;

    const size_t rs = 3072;
    const bf16_t* Qg = qkv + (size_t)b * 1024 * rs + h * 64;
    const bf16_t* Kg = Qg + 1024;
    const bf16_t* Vg = Qg + 2048;
    const float* tabh = tab + h * 2048;

    // stage Q (row-major swizzled), once
    #pragma unroll
    for (int it = 0; it < 2; it++) {
        int c = it * 256 + tid;
        int r = c >> 3, sl = c & 7;
        short8 v = *(const short8*)(Qg + (size_t)(q0 + r) * rs + sl * 8);
        *(short8*)&Qs[r * 64 + ((sl ^ GSWZ(r)) * 8)] = v;
    }
    // stage bias window: lookup index will be (k + 63 - qr_local), range [0,1086]
    {
        int base = 960 - q0;
        #pragma unroll
        for (int it = 0; it < 5; it++) {
            int j = it * 256 + tid;
            if (j < 1087) bias_s[j] = tabh[base + j];
        }
    }
    __syncthreads();

    // Q A-fragments are loop-invariant: row = w*16 + cc, k = ks*32 + cg*8 + 0..7
    short8 qf[2];
    #pragma unroll
    for (int ks = 0; ks < 2; ks++) {
        int r = w * 16 + cc;
        qf[ks] = *(const short8*)&Qs[r * 64 + (((ks * 4 + cg) ^ GSWZ(r)) * 8)];
    }

    f32x4 po[4];                       // O accum, db=0..3 (d = db*16+cc, row = cg*4+j)
    #pragma unroll
    for (int i = 0; i < 4; i++) po[i] = {0.f, 0.f, 0.f, 0.f};
    float m_run[4], l_run[4];
    #pragma unroll
    for (int i = 0; i < 4; i++) { m_run[i] = -1e30f; l_run[i] = 0.f; }

    for (int kt = 0; kt < 16; kt++) {
        const int k0 = kt * 64;
        __syncthreads();  // prior-iter Ks/Vt/Pl reads done

        // stage K row-major swizzled
        #pragma unroll
        for (int it = 0; it < 2; it++) {
            int c = it * 256 + tid;
            int r = c >> 3, sl = c & 7;
            short8 v = *(const short8*)(Kg + (size_t)(k0 + r) * rs + sl * 8);
            *(short8*)&Ks[r * 64 + ((sl ^ GSWZ(r)) * 8)] = v;
        }
        // stage V transposed: Vt[d][key], conflict-free paired b32 writes
        {
            int dq = tid & 7, kp = tid >> 3;  // dq: d-octet, kp: key pair 0..31
            const bf16_t* vp = Vg + (size_t)(k0 + kp * 2) * rs + dq * 8;
            short8 v0 = *(const short8*)vp;
            short8 v1 = *(const short8*)(vp + rs);
            #pragma unroll
            for (int i = 0; i < 8; i++) {
                int d = dq * 8 + i;
                int addr = d * 64 + (((kp >> 2) ^ GSWZ(d)) * 8) + (kp & 3) * 2;
                unsigned int pv = (unsigned int)(unsigned short)v0[i] |
                                  ((unsigned int)(unsigned short)v1[i] << 16);
                *(unsigned int*)&Vt[addr] = pv;
            }
        }
        __syncthreads();

        // S = Q K^T : rows w*16..+16, 4 col-blocks of 16 keys
        f32x4 sc[4];
        #pragma unroll
        for (int cb = 0; cb < 4; cb++) sc[cb] = {0.f, 0.f, 0.f, 0.f};
        #pragma unroll
        for (int ks = 0; ks < 2; ks++)
            #pragma unroll
            for (int cb = 0; cb < 4; cb++) {
                int kr = cb * 16 + cc;
                short8 kf = *(const short8*)&Ks[kr * 64 + (((ks * 4 + cg) ^ GSWZ(kr)) * 8)];
                sc[cb] = __builtin_amdgcn_mfma_f32_16x16x32_bf16(qf[ks], kf, sc[cb], 0, 0, 0);
            }

        // bias + online softmax (stats local to each 16-lane group)
        #pragma unroll
        for (int j = 0; j < 4; j++) {
            int qr = w * 16 + cg * 4 + j;          // local q row 0..63
            int bbase = k0 + cc - qr + 63;
            float s0 = sc[0][j] + bias_s[bbase];
            float s1 = sc[1][j] + bias_s[bbase + 16];
            float s2 = sc[2][j] + bias_s[bbase + 32];
            float s3 = sc[3][j] + bias_s[bbase + 48];
            float tm = fmaxf(fmaxf(s0, s1), fmaxf(s2, s3));
            tm = fmaxf(tm, __shfl_xor(tm, 1));
            tm = fmaxf(tm, __shfl_xor(tm, 2));
            tm = fmaxf(tm, __shfl_xor(tm, 4));
            tm = fmaxf(tm, __shfl_xor(tm, 8));
            float mn = fmaxf(m_run[j], tm);
            float scale = __expf(m_run[j] - mn);
            s0 = __expf(s0 - mn); s1 = __expf(s1 - mn);
            s2 = __expf(s2 - mn); s3 = __expf(s3 - mn);
            float rsum = s0 + s1 + s2 + s3;
            rsum += __shfl_xor(rsum, 1);
            rsum += __shfl_xor(rsum, 2);
            rsum += __shfl_xor(rsum, 4);
            rsum += __shfl_xor(rsum, 8);
            m_run[j] = mn;
            l_run[j] = l_run[j] * scale + rsum;
            #pragma unroll
            for (int db = 0; db < 4; db++) po[db][j] *= scale;
            // P -> LDS (bf16, swizzled row-major)
            float pvals[4] = {s0, s1, s2, s3};
            #pragma unroll
            for (int cb = 0; cb < 4; cb++) {
                int key = cb * 16 + cc;
                int slot = (key >> 3);
                Pl[qr * 64 + ((slot ^ GSWZ(qr)) * 8) + (key & 7)] = f2b_rne(pvals[cb]);
            }
        }
        __syncthreads();  // P visible to all lanes

        // O += P V : A = P rows w*16+cc, B = Vt rows d
        #pragma unroll
        for (int ks = 0; ks < 2; ks++) {
            int r = w * 16 + cc;
            short8 pf = *(const short8*)&Pl[r * 64 + (((ks * 4 + cg) ^ GSWZ(r)) * 8)];
            #pragma unroll
            for (int db = 0; db < 4; db++) {
                int dr = db * 16 + cc;
                short8 vf = *(const short8*)&Vt[dr * 64 + (((ks * 4 + cg) ^ GSWZ(dr)) * 8)];
                po[db] = __builtin_amdgcn_mfma_f32_16x16x32_bf16(pf, vf, po[db], 0, 0, 0);
            }
        }
    }

    // epilogue: normalize, write bf16 [B,S,INNER]
    bf16_t* outp = attn_out + ((size_t)b * 1024 + q0) * 1024 + h * 64;
    #pragma unroll
    for (int j = 0; j < 4; j++) {
        float inv = 1.f / l_run[j];
        int qr = w * 16 + cg * 4 + j;
        #pragma unroll
        for (int db = 0; db < 4; db++)
            outp[(size_t)qr * 1024 + db * 16 + cc] = f2b_rne(po[db][j] * inv);
    }
}

// ---------------------------------------------------------------------------
extern "C" void kernel_launch(void* const* d_in, const int* in_sizes, int n_in,
                              void* d_out, int out_size, void* d_ws, size_t ws_size,
                              hipStream_t stream) {
    const float* hs   = (const float*)d_in[0];  // [8,1024,1024]
    const float* wqkv = (const float*)d_in[1];  // [3072,1024]
    const float* emb  = (const float*)d_in[2];  // [32,16]
    const float* wout = (const float*)d_in[3];  // [1024,1024]
    float* out = (float*)d_out;                 // [8,1024,1024] fp32

    char* p = (char*)d_ws;
    bf16_t* qkvb  = (bf16_t*)p; p += (size_t)8192 * 3072 * 2;  // 48 MB
    bf16_t* attnb = (bf16_t*)p; p += (size_t)8192 * 1024 * 2;  // 16 MB
    bf16_t* hsb   = (bf16_t*)p; p += (size_t)8192 * 1024 * 2;  // 16 MB
    bf16_t* wqkvb = (bf16_t*)p; p += (size_t)3072 * 1024 * 2;  //  6 MB
    bf16_t* woutb = (bf16_t*)p; p += (size_t)1024 * 1024 * 2;  //  2 MB
    float*  tab   = (float*)p;                                 // 128 KB

    f2b_kernel<<<2048, 256, 0, stream>>>(hs, hsb, 8192 * 1024 / 4);
    f2b_kernel<<<768, 256, 0, stream>>>(wqkv, wqkvb, 3072 * 1024 / 4);
    f2b_kernel<<<256, 256, 0, stream>>>(wout, woutb, 1024 * 1024 / 4);
    build_bias_tab<<<8, 256, 0, stream>>>(emb, tab);

    gemm_mfma<bf16_t><<<dim3(3072 / 128, 8192 / 128), 256, 0, stream>>>(hsb, wqkvb, qkvb, 3072);
    attn_mfma<<<dim3(16, 16, 8), 256, 0, stream>>>(qkvb, tab, attnb);
    gemm_mfma<float><<<dim3(1024 / 128, 8192 / 128), 256, 0, stream>>>(attnb, woutb, out, 1024);
}